// Round 2
// baseline (3095.004 us; speedup 1.0000x reference)
//
#include <hip/hip_runtime.h>
#include <hip/hip_bf16.h>

#define NB 16
#define SS 512
#define MC 16
#define NN 64
#define HD 1024

__device__ __forceinline__ float gelu_f(float v){
    return 0.5f * v * (1.0f + erff(v * 0.70710678118654752f));
}

// ---------- embedding (padding_idx=0) + layernorm -> h[B,M,S,N] ----------
__global__ __launch_bounds__(256) void k_embed_ln(
    const int* __restrict__ x, const float* __restrict__ emb,
    const float* __restrict__ g, const float* __restrict__ bta,
    float* __restrict__ h)
{
    int bs = blockIdx.x;            // b*S + s
    int b = bs >> 9, s = bs & 511;
    int t = x[bs];
    int tid = threadIdx.x;
    float v[4];
    #pragma unroll
    for (int j = 0; j < 4; ++j){
        int idx = tid + j*256;
        v[j] = (t == 0) ? 0.0f : emb[(size_t)t*HD + idx];
    }
    float sum = v[0]+v[1]+v[2]+v[3];
    float sq  = v[0]*v[0]+v[1]*v[1]+v[2]*v[2]+v[3]*v[3];
    __shared__ float red[2][4];
    int lane = tid & 63, wid = tid >> 6;
    #pragma unroll
    for (int off = 32; off; off >>= 1){
        sum += __shfl_down(sum, off, 64);
        sq  += __shfl_down(sq,  off, 64);
    }
    if (lane == 0){ red[0][wid] = sum; red[1][wid] = sq; }
    __syncthreads();
    sum = red[0][0]+red[0][1]+red[0][2]+red[0][3];
    sq  = red[1][0]+red[1][1]+red[1][2]+red[1][3];
    float mean = sum * (1.0f/HD);
    float var  = sq  * (1.0f/HD) - mean*mean;
    float rs = rsqrtf(var + 1e-5f);
    #pragma unroll
    for (int j = 0; j < 4; ++j){
        int idx = tid + j*256;
        float y = (v[j]-mean)*rs*g[idx] + bta[idx];
        int m = idx >> 6, n = idx & 63;
        h[((size_t)(b*MC + m)*SS + s)*NN + n] = y;
    }
}

// ---------- 3x3 SAME conv [B,16,S,N]->[B,16,S,N], + bias, gelu, optional residual ----------
__global__ __launch_bounds__(256) void k_conv(
    const float* __restrict__ in, const float* __restrict__ w,
    const float* __restrict__ bias, const float* residual, float* out)
{
    int bid = blockIdx.x;
    int b  = bid >> 7;              // /128
    int y0 = (bid & 127) * 4;
    int tid = threadIdx.x;
    __shared__ float sw[16*16*9];
    __shared__ float sin_t[16][6][66];
    for (int idx = tid; idx < 2304; idx += 256) sw[idx] = w[idx];
    for (int idx = tid; idx < 16*6*66; idx += 256){
        int i   = idx / 396;
        int rem = idx - i*396;
        int r = rem / 66, c = rem - r*66;
        int yy = y0 - 1 + r;
        float val = 0.0f;
        if (c >= 1 && c <= 64 && yy >= 0 && yy < SS)
            val = in[((size_t)(b*16 + i)*SS + yy)*64 + (c-1)];
        sin_t[i][r][c] = val;
    }
    __syncthreads();
    int o = tid >> 4, ng = tid & 15;
    float acc[4][4] = {};
    for (int i = 0; i < 16; ++i){
        #pragma unroll
        for (int ky = 0; ky < 3; ++ky){
            #pragma unroll
            for (int kx = 0; kx < 3; ++kx){
                float wv = sw[(o*16+i)*9 + ky*3 + kx];
                #pragma unroll
                for (int dy = 0; dy < 4; ++dy){
                    #pragma unroll
                    for (int jj = 0; jj < 4; ++jj){
                        acc[dy][jj] += wv * sin_t[i][dy+ky][ng*4 + jj + kx];
                    }
                }
            }
        }
    }
    float bv = bias[o];
    #pragma unroll
    for (int dy = 0; dy < 4; ++dy){
        #pragma unroll
        for (int jj = 0; jj < 4; ++jj){
            int n = ng*4 + jj;
            size_t oidx = ((size_t)(b*16 + o)*SS + (y0+dy))*64 + n;
            float val = gelu_f(acc[dy][jj] + bv);
            if (residual) val += residual[oidx];
            out[oidx] = val;
        }
    }
}

// ---------- QK^T: score[b,s1,s2] = sum_{oc,n} q[b,oc,s1,n]*k[b,oc,s2,n] ----------
__global__ __launch_bounds__(256) void k_qk(
    const float* __restrict__ q, const float* __restrict__ k,
    float* __restrict__ score)
{
    int bid = blockIdx.x;
    int b = bid >> 6;
    int t = bid & 63;
    int s1_0 = (t >> 3) * 64, s2_0 = (t & 7) * 64;
    __shared__ float qa[64][68], kb[64][68];
    int tid = threadIdx.x;
    int ty = tid >> 4, tx = tid & 15;
    float acc[4][4] = {};
    for (int oc = 0; oc < 16; ++oc){
        const float* qp = q + ((size_t)(b*16+oc)*SS + s1_0)*64;
        const float* kp = k + ((size_t)(b*16+oc)*SS + s2_0)*64;
        #pragma unroll
        for (int l = 0; l < 16; ++l){
            int idx = tid + l*256;
            int r = idx >> 6, c = idx & 63;
            qa[r][c] = qp[r*64 + c];
            kb[r][c] = kp[r*64 + c];
        }
        __syncthreads();
        #pragma unroll 4
        for (int kk = 0; kk < 64; kk += 4){
            float4 av[4], bv[4];
            #pragma unroll
            for (int i = 0; i < 4; ++i) av[i] = *(const float4*)&qa[ty*4+i][kk];
            #pragma unroll
            for (int j = 0; j < 4; ++j) bv[j] = *(const float4*)&kb[tx*4+j][kk];
            #pragma unroll
            for (int i = 0; i < 4; ++i)
                #pragma unroll
                for (int j = 0; j < 4; ++j)
                    acc[i][j] += av[i].x*bv[j].x + av[i].y*bv[j].y
                               + av[i].z*bv[j].z + av[i].w*bv[j].w;
        }
        __syncthreads();
    }
    #pragma unroll
    for (int i = 0; i < 4; ++i){
        int s1 = s1_0 + ty*4 + i;
        float4 o4 = make_float4(acc[i][0],acc[i][1],acc[i][2],acc[i][3]);
        *(float4*)&score[((size_t)b*SS + s1)*SS + s2_0 + tx*4] = o4;
    }
}

// ---------- softmax over batch axis (16 values per (s1,s2)) ----------
__global__ __launch_bounds__(256) void k_softmax_b(float* __restrict__ score)
{
    int sid = blockIdx.x*256 + threadIdx.x;     // 0..262143
    float vals[16];
    float m = -1e30f;
    #pragma unroll
    for (int b = 0; b < 16; ++b){
        vals[b] = score[(size_t)b*SS*SS + sid];
        m = fmaxf(m, vals[b]);
    }
    float sum = 0.f;
    #pragma unroll
    for (int b = 0; b < 16; ++b){ vals[b] = __expf(vals[b]-m); sum += vals[b]; }
    float inv = 1.0f/sum;
    #pragma unroll
    for (int b = 0; b < 16; ++b) score[(size_t)b*SS*SS + sid] = vals[b]*inv;
}

// ---------- o[b,s1,d] = sum_{s2} score[b,s1,s2] * v[b, d>>6, s2, d&63] ----------
__global__ __launch_bounds__(256) void k_sv(
    const float* __restrict__ score, const float* __restrict__ v,
    float* __restrict__ o)
{
    int bid = blockIdx.x;            // b*128 + s1t*16 + dt
    int b = bid >> 7;
    int s1_0 = ((bid >> 4) & 7) * 64;
    int dt = bid & 15;
    __shared__ float sa[64][68], vb[64][68];
    int tid = threadIdx.x;
    int ty = tid >> 4, tx = tid & 15;
    float acc[4][4] = {};
    for (int ch = 0; ch < 8; ++ch){
        int s2_0 = ch*64;
        const float* sp = score + ((size_t)b*SS + s1_0)*SS + s2_0;
        const float* vp = v + ((size_t)(b*16+dt)*SS + s2_0)*64;
        #pragma unroll
        for (int l = 0; l < 16; ++l){
            int idx = tid + l*256;
            int r = idx >> 6, c = idx & 63;
            sa[r][c] = sp[(size_t)r*SS + c];
            vb[r][c] = vp[r*64 + c];
        }
        __syncthreads();
        #pragma unroll 4
        for (int kk = 0; kk < 64; kk += 4){
            float4 av[4], bv[4];
            #pragma unroll
            for (int i = 0; i < 4; ++i) av[i] = *(const float4*)&sa[ty*4+i][kk];
            #pragma unroll
            for (int l2 = 0; l2 < 4; ++l2) bv[l2] = *(const float4*)&vb[kk+l2][tx*4];
            #pragma unroll
            for (int i = 0; i < 4; ++i){
                acc[i][0] += av[i].x*bv[0].x + av[i].y*bv[1].x + av[i].z*bv[2].x + av[i].w*bv[3].x;
                acc[i][1] += av[i].x*bv[0].y + av[i].y*bv[1].y + av[i].z*bv[2].y + av[i].w*bv[3].y;
                acc[i][2] += av[i].x*bv[0].z + av[i].y*bv[1].z + av[i].z*bv[2].z + av[i].w*bv[3].z;
                acc[i][3] += av[i].x*bv[0].w + av[i].y*bv[1].w + av[i].z*bv[2].w + av[i].w*bv[3].w;
            }
        }
        __syncthreads();
    }
    #pragma unroll
    for (int i = 0; i < 4; ++i){
        int s1 = s1_0 + ty*4 + i;
        float4 o4 = make_float4(acc[i][0],acc[i][1],acc[i][2],acc[i][3]);
        *(float4*)&o[((size_t)b*SS + s1)*1024 + dt*64 + tx*4] = o4;
    }
}

// ---------- layernorm over DN=1024 + transpose to [B,OD,S,N] ----------
__global__ __launch_bounds__(256) void k_ln2(
    const float* __restrict__ o, const float* __restrict__ g,
    const float* __restrict__ bta, float* __restrict__ oc)
{
    int bs = blockIdx.x;            // b*S + s
    int b = bs >> 9, s = bs & 511;
    int tid = threadIdx.x;
    const float* row = o + (size_t)bs*1024;
    float v[4];
    #pragma unroll
    for (int j = 0; j < 4; ++j) v[j] = row[tid + j*256];
    float sum = v[0]+v[1]+v[2]+v[3];
    float sq  = v[0]*v[0]+v[1]*v[1]+v[2]*v[2]+v[3]*v[3];
    __shared__ float red[2][4];
    int lane = tid & 63, wid = tid >> 6;
    #pragma unroll
    for (int off = 32; off; off >>= 1){
        sum += __shfl_down(sum, off, 64);
        sq  += __shfl_down(sq,  off, 64);
    }
    if (lane == 0){ red[0][wid] = sum; red[1][wid] = sq; }
    __syncthreads();
    sum = red[0][0]+red[0][1]+red[0][2]+red[0][3];
    sq  = red[1][0]+red[1][1]+red[1][2]+red[1][3];
    float mean = sum * (1.0f/1024.0f);
    float var  = sq  * (1.0f/1024.0f) - mean*mean;
    float rs = rsqrtf(var + 1e-5f);
    #pragma unroll
    for (int j = 0; j < 4; ++j){
        int idx = tid + j*256;
        float y = (v[j]-mean)*rs*g[idx] + bta[idx];
        int ch = idx >> 6, n = idx & 63;
        oc[((size_t)(b*16 + ch)*SS + s)*64 + n] = y;
    }
}

extern "C" void kernel_launch(void* const* d_in, const int* in_sizes, int n_in,
                              void* d_out, int out_size, void* d_ws, size_t ws_size,
                              hipStream_t stream)
{
    const int*   x    = (const int*)  d_in[0];
    const float* emb  = (const float*)d_in[1];
    const float* g0   = (const float*)d_in[2];
    const float* b0   = (const float*)d_in[3];
    const float* qw   = (const float*)d_in[4];
    const float* qb   = (const float*)d_in[5];
    const float* kw   = (const float*)d_in[6];
    const float* kb   = (const float*)d_in[7];
    const float* vw   = (const float*)d_in[8];
    const float* vb   = (const float*)d_in[9];
    const float* lng  = (const float*)d_in[10];
    const float* lnb  = (const float*)d_in[11];
    const float* cw   = (const float*)d_in[12];
    const float* cb   = (const float*)d_in[13];
    float* out = (float*)d_out;   // reference output dtype is float32

    float* ws = (float*)d_ws;
    const size_t TS = (size_t)16*16*512*64;   // 8388608 elems per tensor
    float* q  = ws;
    float* k  = ws + TS;
    float* v  = ws + 2*TS;
    float* sc = ws + 3*TS;                    // [16,512,512] = 4194304 floats

    // h tensors live directly in d_out:
    //   out slice 0: h_final; slice 1+i: h before layer i
    float* hbuf[5];
    hbuf[0] = out + 1*TS;  // h0 (input to layer 0)
    hbuf[1] = out + 2*TS;
    hbuf[2] = out + 3*TS;
    hbuf[3] = out + 4*TS;
    hbuf[4] = out;         // h_final

    k_embed_ln<<<8192, 256, 0, stream>>>(x, emb, g0, b0, hbuf[0]);
    for (int i = 0; i < 4; ++i){
        const float* h = hbuf[i];
        float* hn = hbuf[i+1];
        k_conv<<<2048, 256, 0, stream>>>(h, qw + i*2304, qb + i*16, nullptr, q);
        k_conv<<<2048, 256, 0, stream>>>(h, kw + i*2304, kb + i*16, nullptr, k);
        k_conv<<<2048, 256, 0, stream>>>(h, vw + i*2304, vb + i*16, nullptr, v);
        k_qk<<<1024, 256, 0, stream>>>(q, k, sc);
        k_softmax_b<<<1024, 256, 0, stream>>>(sc);
        k_sv<<<2048, 256, 0, stream>>>(sc, v, q);                          // o_pre -> q buf
        k_ln2<<<8192, 256, 0, stream>>>(q, lng + i*1024, lnb + i*1024, k); // o_conv -> k buf
        k_conv<<<2048, 256, 0, stream>>>(k, cw + i*2304, cb + i*16, h, hn); // + residual
    }
}

// Round 3
// 1349.926 us; speedup vs baseline: 2.2927x; 2.2927x over previous
//
#include <hip/hip_runtime.h>
#include <hip/hip_bf16.h>

typedef unsigned short u16;
typedef unsigned int   u32;
typedef short bf16x8 __attribute__((ext_vector_type(8)));
typedef float f32x4  __attribute__((ext_vector_type(4)));

#define SS 512

__device__ __forceinline__ float gelu_f(float v){
    return 0.5f * v * (1.0f + erff(v * 0.70710678118654752f));
}
__device__ __forceinline__ u16 bf16_rne(float v){
    u32 u = __float_as_uint(v);
    u32 r = u + 0x7FFF + ((u >> 16) & 1);
    return (u16)(r >> 16);
}

// ---------- embedding (padding_idx=0) + layernorm -> h[B,M,S,N] ----------
__global__ __launch_bounds__(256) void k_embed_ln(
    const int* __restrict__ x, const float* __restrict__ emb,
    const float* __restrict__ g, const float* __restrict__ bta,
    float* __restrict__ h)
{
    int bs = blockIdx.x;
    int b = bs >> 9, s = bs & 511;
    int t = x[bs];
    int tid = threadIdx.x;
    float v[4];
    #pragma unroll
    for (int j = 0; j < 4; ++j){
        int idx = tid + j*256;
        v[j] = (t == 0) ? 0.0f : emb[(size_t)t*1024 + idx];
    }
    float sum = v[0]+v[1]+v[2]+v[3];
    float sq  = v[0]*v[0]+v[1]*v[1]+v[2]*v[2]+v[3]*v[3];
    __shared__ float red[2][4];
    int lane = tid & 63, wid = tid >> 6;
    #pragma unroll
    for (int off = 32; off; off >>= 1){
        sum += __shfl_down(sum, off, 64);
        sq  += __shfl_down(sq,  off, 64);
    }
    if (lane == 0){ red[0][wid] = sum; red[1][wid] = sq; }
    __syncthreads();
    sum = red[0][0]+red[0][1]+red[0][2]+red[0][3];
    sq  = red[1][0]+red[1][1]+red[1][2]+red[1][3];
    float mean = sum * (1.0f/1024.0f);
    float var  = sq  * (1.0f/1024.0f) - mean*mean;
    float rs = rsqrtf(var + 1e-5f);
    #pragma unroll
    for (int j = 0; j < 4; ++j){
        int idx = tid + j*256;
        float y = (v[j]-mean)*rs*g[idx] + bta[idx];
        int m = idx >> 6, n = idx & 63;
        h[((size_t)(b*16 + m)*SS + s)*64 + n] = y;
    }
}

// ---------- 3x3 SAME conv, bias, gelu; outputs: f32 and/or bf16 hi/lo split ----------
__global__ __launch_bounds__(256) void k_conv(
    const float* __restrict__ in, const float* __restrict__ w,
    const float* __restrict__ bias, const float* __restrict__ residual,
    float* __restrict__ outf, u16* __restrict__ outh, u16* __restrict__ outl)
{
    int bid = blockIdx.x;
    int b  = bid >> 7;
    int y0 = (bid & 127) * 4;
    int tid = threadIdx.x;
    __shared__ float sw[2304];
    __shared__ float sin_t[16][6][72];   // col c = n + 4; halos at c=3 (n=-1), c=68 (n=64)
    for (int idx = tid; idx < 2304; idx += 256) sw[idx] = w[idx];
    if (tid < 96){
        int ch = tid / 6, r = tid - ch*6;
        sin_t[ch][r][3]  = 0.0f;
        sin_t[ch][r][68] = 0.0f;
    }
    #pragma unroll
    for (int i = 0; i < 6; ++i){
        int idx = tid + i*256;            // 0..1535
        int ch  = idx / 96;
        int rem = idx - ch*96;
        int r = rem >> 4, f = rem & 15;
        int yy = y0 - 1 + r;
        float4 v4 = make_float4(0.f,0.f,0.f,0.f);
        if (yy >= 0 && yy < SS)
            v4 = *(const float4*)(in + ((size_t)(b*16+ch)*SS + yy)*64 + f*4);
        *(float4*)&sin_t[ch][r][4 + f*4] = v4;
    }
    __syncthreads();
    int o = tid >> 4, ng = tid & 15;
    float acc[4][4] = {};
    for (int i = 0; i < 16; ++i){
        #pragma unroll
        for (int ky = 0; ky < 3; ++ky){
            #pragma unroll
            for (int kx = 0; kx < 3; ++kx){
                float wv = sw[(o*16+i)*9 + ky*3 + kx];
                #pragma unroll
                for (int dy = 0; dy < 4; ++dy){
                    #pragma unroll
                    for (int jj = 0; jj < 4; ++jj){
                        acc[dy][jj] += wv * sin_t[i][dy+ky][ng*4 + jj + kx + 3];
                    }
                }
            }
        }
    }
    float bv = bias[o];
    #pragma unroll
    for (int dy = 0; dy < 4; ++dy){
        size_t obase = ((size_t)(b*16 + o)*SS + (y0+dy))*64 + ng*4;
        float r0[4];
        float4 rr = make_float4(0.f,0.f,0.f,0.f);
        if (residual) rr = *(const float4*)&residual[obase];
        r0[0] = gelu_f(acc[dy][0] + bv) + rr.x;
        r0[1] = gelu_f(acc[dy][1] + bv) + rr.y;
        r0[2] = gelu_f(acc[dy][2] + bv) + rr.z;
        r0[3] = gelu_f(acc[dy][3] + bv) + rr.w;
        if (outf) *(float4*)&outf[obase] = make_float4(r0[0],r0[1],r0[2],r0[3]);
        if (outh){
            u16 hh[4], ll[4];
            #pragma unroll
            for (int jj = 0; jj < 4; ++jj){
                u16 hv = bf16_rne(r0[jj]);
                float hf = __uint_as_float((u32)hv << 16);
                hh[jj] = hv;
                ll[jj] = bf16_rne(r0[jj] - hf);
            }
            uint2 ph = make_uint2((u32)hh[0] | ((u32)hh[1]<<16), (u32)hh[2] | ((u32)hh[3]<<16));
            uint2 pl = make_uint2((u32)ll[0] | ((u32)ll[1]<<16), (u32)ll[2] | ((u32)ll[3]<<16));
            *(uint2*)&outh[obase] = ph;
            *(uint2*)&outl[obase] = pl;
        }
    }
}

// ---------- QK^T via MFMA, split-bf16 (3 products) ----------
// score[b,s1,s2] = sum_d q2[s1,d] k2[s2,d];  q stored as hi/lo bf16 [b][oc][s][n]
__global__ __launch_bounds__(256) void k_qk_mfma(
    const u16* __restrict__ qh, const u16* __restrict__ ql,
    const u16* __restrict__ kh, const u16* __restrict__ kl,
    float* __restrict__ score)
{
    int bid = blockIdx.x;                 // 16b x 4 s1t x 8 s2t = 512
    int b = bid >> 5;
    int s1_0 = ((bid >> 3) & 3) * 128;
    int s2_0 = (bid & 7) * 64;
    __shared__ u16 Ah[128][72], Al[128][72], Bh[64][72], Bl[64][72];
    int tid = threadIdx.x;
    int w = tid >> 6, lane = tid & 63;
    int l15 = lane & 15, l4 = lane >> 4;
    f32x4 acc[2][4];
    #pragma unroll
    for (int r=0;r<2;++r)
        #pragma unroll
        for(int c=0;c<4;++c) acc[r][c] = (f32x4){0.f,0.f,0.f,0.f};

    for (int oc = 0; oc < 16; ++oc){
        size_t qbase = ((size_t)(b*16+oc)*SS + s1_0)*64;
        size_t kbase = ((size_t)(b*16+oc)*SS + s2_0)*64;
        #pragma unroll
        for (int i = 0; i < 4; ++i){      // A: 128 rows x 8 chunks = 1024
            int idx = tid + i*256;
            int r = idx >> 3, f = idx & 7;
            *(uint4*)&Ah[r][f*8] = *(const uint4*)(qh + qbase + (size_t)r*64 + f*8);
            *(uint4*)&Al[r][f*8] = *(const uint4*)(ql + qbase + (size_t)r*64 + f*8);
        }
        #pragma unroll
        for (int i = 0; i < 2; ++i){      // B: 64 rows x 8 chunks = 512
            int idx = tid + i*256;
            int r = idx >> 3, f = idx & 7;
            *(uint4*)&Bh[r][f*8] = *(const uint4*)(kh + kbase + (size_t)r*64 + f*8);
            *(uint4*)&Bl[r][f*8] = *(const uint4*)(kl + kbase + (size_t)r*64 + f*8);
        }
        __syncthreads();
        #pragma unroll
        for (int ks = 0; ks < 2; ++ks){
            bf16x8 ah[2], al[2];
            #pragma unroll
            for (int r=0;r<2;++r){
                ah[r] = *(const bf16x8*)&Ah[w*32 + r*16 + l15][ks*32 + l4*8];
                al[r] = *(const bf16x8*)&Al[w*32 + r*16 + l15][ks*32 + l4*8];
            }
            #pragma unroll
            for (int c=0;c<4;++c){
                bf16x8 bh = *(const bf16x8*)&Bh[c*16 + l15][ks*32 + l4*8];
                bf16x8 bl = *(const bf16x8*)&Bl[c*16 + l15][ks*32 + l4*8];
                #pragma unroll
                for (int r=0;r<2;++r){
                    acc[r][c] = __builtin_amdgcn_mfma_f32_16x16x32_bf16(ah[r], bh, acc[r][c],0,0,0);
                    acc[r][c] = __builtin_amdgcn_mfma_f32_16x16x32_bf16(al[r], bh, acc[r][c],0,0,0);
                    acc[r][c] = __builtin_amdgcn_mfma_f32_16x16x32_bf16(ah[r], bl, acc[r][c],0,0,0);
                }
            }
        }
        __syncthreads();
    }
    #pragma unroll
    for (int r=0;r<2;++r){
        #pragma unroll
        for (int c=0;c<4;++c){
            #pragma unroll
            for (int i=0;i<4;++i){
                int s1 = s1_0 + w*32 + r*16 + l4*4 + i;
                int s2 = s2_0 + c*16 + l15;
                score[((size_t)b*SS + s1)*SS + s2] = acc[r][c][i];
            }
        }
    }
}

// ---------- vT[b][d][s2] (bf16) from v[b][oc][s2][n] (f32), d = oc*64+n ----------
__global__ __launch_bounds__(256) void k_vT(
    const float* __restrict__ v, u16* __restrict__ vT)
{
    int bid = blockIdx.x;                 // 16b x 16oc x 8 s2blk = 2048
    int b  = bid >> 7;
    int oc = (bid >> 3) & 15;
    int sb = bid & 7;
    int tid = threadIdx.x;
    int n  = tid & 63;
    int sg = tid >> 6;
    int s2base = sb*64 + sg*16;
    const float* src = v + ((size_t)(b*16+oc)*SS + s2base)*64 + n;
    union { u16 u[16]; uint4 q[2]; } pk;
    #pragma unroll
    for (int j = 0; j < 16; ++j)
        pk.u[j] = bf16_rne(src[(size_t)j*64]);
    u16* dst = vT + ((size_t)b*1024 + oc*64 + n)*SS + s2base;
    *(uint4*)dst       = pk.q[0];
    *(uint4*)(dst + 8) = pk.q[1];
}

// ---------- softmax over batch axis; writes bf16 probs ----------
__global__ __launch_bounds__(256) void k_softmax_b(
    const float* __restrict__ score, u16* __restrict__ scb)
{
    int sid = blockIdx.x*256 + threadIdx.x;     // 0..262143
    float vals[16];
    float m = -1e30f;
    #pragma unroll
    for (int b = 0; b < 16; ++b){
        vals[b] = score[(size_t)b*SS*SS + sid];
        m = fmaxf(m, vals[b]);
    }
    float sum = 0.f;
    #pragma unroll
    for (int b = 0; b < 16; ++b){ vals[b] = __expf(vals[b]-m); sum += vals[b]; }
    float inv = 1.0f/sum;
    #pragma unroll
    for (int b = 0; b < 16; ++b) scb[(size_t)b*SS*SS + sid] = bf16_rne(vals[b]*inv);
}

// ---------- o_pre[b,s1,d] = sum_s2 P[b,s1,s2] * vT[b,d,s2]  (MFMA bf16) ----------
__global__ __launch_bounds__(256) void k_sv_mfma(
    const u16* __restrict__ scb, const u16* __restrict__ vT,
    float* __restrict__ o)
{
    int bid = blockIdx.x;                 // 16b x 4 s1t x 16 dt = 1024
    int b = bid >> 6;
    int s1_0 = ((bid >> 4) & 3) * 128;
    int d0 = (bid & 15) * 64;
    __shared__ u16 As[128][72], Bs[64][72];
    int tid = threadIdx.x;
    int w = tid >> 6, lane = tid & 63;
    int l15 = lane & 15, l4 = lane >> 4;
    f32x4 acc[2][4];
    #pragma unroll
    for (int r=0;r<2;++r)
        #pragma unroll
        for(int c=0;c<4;++c) acc[r][c] = (f32x4){0.f,0.f,0.f,0.f};

    for (int st = 0; st < 8; ++st){       // K = 512 over s2, step 64
        int s2b = st*64;
        #pragma unroll
        for (int i = 0; i < 4; ++i){      // A: 128 rows x 8 chunks
            int idx = tid + i*256;
            int r = idx >> 3, f = idx & 7;
            *(uint4*)&As[r][f*8] = *(const uint4*)(scb + ((size_t)b*SS + s1_0 + r)*SS + s2b + f*8);
        }
        #pragma unroll
        for (int i = 0; i < 2; ++i){      // B: 64 rows x 8 chunks
            int idx = tid + i*256;
            int r = idx >> 3, f = idx & 7;
            *(uint4*)&Bs[r][f*8] = *(const uint4*)(vT + ((size_t)b*1024 + d0 + r)*SS + s2b + f*8);
        }
        __syncthreads();
        #pragma unroll
        for (int ks = 0; ks < 2; ++ks){
            bf16x8 a0[2];
            #pragma unroll
            for (int r=0;r<2;++r)
                a0[r] = *(const bf16x8*)&As[w*32 + r*16 + l15][ks*32 + l4*8];
            #pragma unroll
            for (int c=0;c<4;++c){
                bf16x8 b0 = *(const bf16x8*)&Bs[c*16 + l15][ks*32 + l4*8];
                #pragma unroll
                for (int r=0;r<2;++r)
                    acc[r][c] = __builtin_amdgcn_mfma_f32_16x16x32_bf16(a0[r], b0, acc[r][c],0,0,0);
            }
        }
        __syncthreads();
    }
    #pragma unroll
    for (int r=0;r<2;++r){
        #pragma unroll
        for (int c=0;c<4;++c){
            #pragma unroll
            for (int i=0;i<4;++i){
                int s1 = s1_0 + w*32 + r*16 + l4*4 + i;
                o[((size_t)b*SS + s1)*1024 + d0 + c*16 + l15] = acc[r][c][i];
            }
        }
    }
}

// ---------- layernorm over DN=1024 + transpose to [B,OD,S,N] ----------
__global__ __launch_bounds__(256) void k_ln2(
    const float* __restrict__ o, const float* __restrict__ g,
    const float* __restrict__ bta, float* __restrict__ oc)
{
    int bs = blockIdx.x;
    int b = bs >> 9, s = bs & 511;
    int tid = threadIdx.x;
    const float* row = o + (size_t)bs*1024;
    float v[4];
    #pragma unroll
    for (int j = 0; j < 4; ++j) v[j] = row[tid + j*256];
    float sum = v[0]+v[1]+v[2]+v[3];
    float sq  = v[0]*v[0]+v[1]*v[1]+v[2]*v[2]+v[3]*v[3];
    __shared__ float red[2][4];
    int lane = tid & 63, wid = tid >> 6;
    #pragma unroll
    for (int off = 32; off; off >>= 1){
        sum += __shfl_down(sum, off, 64);
        sq  += __shfl_down(sq,  off, 64);
    }
    if (lane == 0){ red[0][wid] = sum; red[1][wid] = sq; }
    __syncthreads();
    sum = red[0][0]+red[0][1]+red[0][2]+red[0][3];
    sq  = red[1][0]+red[1][1]+red[1][2]+red[1][3];
    float mean = sum * (1.0f/1024.0f);
    float var  = sq  * (1.0f/1024.0f) - mean*mean;
    float rs = rsqrtf(var + 1e-5f);
    #pragma unroll
    for (int j = 0; j < 4; ++j){
        int idx = tid + j*256;
        float y = (v[j]-mean)*rs*g[idx] + bta[idx];
        int ch = idx >> 6, n = idx & 63;
        oc[((size_t)(b*16 + ch)*SS + s)*64 + n] = y;
    }
}

extern "C" void kernel_launch(void* const* d_in, const int* in_sizes, int n_in,
                              void* d_out, int out_size, void* d_ws, size_t ws_size,
                              hipStream_t stream)
{
    const int*   x    = (const int*)  d_in[0];
    const float* emb  = (const float*)d_in[1];
    const float* g0   = (const float*)d_in[2];
    const float* b0   = (const float*)d_in[3];
    const float* qw   = (const float*)d_in[4];
    const float* qb   = (const float*)d_in[5];
    const float* kw   = (const float*)d_in[6];
    const float* kb   = (const float*)d_in[7];
    const float* vw   = (const float*)d_in[8];
    const float* vb   = (const float*)d_in[9];
    const float* lng  = (const float*)d_in[10];
    const float* lnb  = (const float*)d_in[11];
    const float* cw   = (const float*)d_in[12];
    const float* cb   = (const float*)d_in[13];
    float* out = (float*)d_out;

    const size_t TS = (size_t)16*16*512*64;   // 8388608
    char* wsb = (char*)d_ws;
    u16*  qh = (u16*)wsb;                 // [0, 2TS) bytes
    u16*  ql = qh + TS;
    u16*  kh = ql + TS;
    u16*  kl = kh + TS;
    float* v  = (float*)(wsb + 8*TS);     // f32, TS elems
    float* sc = v + TS;                   // f32, TS/2 elems (16*512*512)
    // aliases (liveness-checked): after qk, ql->vT, kh->scb; after vT, v->o_pre;
    // after sv, [qh,ql] region (2TS u16 = TS f32) -> ln2 output
    u16*  vTb  = ql;
    u16*  scb  = kh;
    float* o_pre = v;
    float* oc_buf = (float*)wsb;

    float* hbuf[5];
    hbuf[0] = out + 1*TS;
    hbuf[1] = out + 2*TS;
    hbuf[2] = out + 3*TS;
    hbuf[3] = out + 4*TS;
    hbuf[4] = out;

    k_embed_ln<<<8192, 256, 0, stream>>>(x, emb, g0, b0, hbuf[0]);
    for (int i = 0; i < 4; ++i){
        const float* h = hbuf[i];
        float* hn = hbuf[i+1];
        k_conv<<<2048, 256, 0, stream>>>(h, qw + i*2304, qb + i*16, nullptr, nullptr, qh, ql);
        k_conv<<<2048, 256, 0, stream>>>(h, kw + i*2304, kb + i*16, nullptr, nullptr, kh, kl);
        k_conv<<<2048, 256, 0, stream>>>(h, vw + i*2304, vb + i*16, nullptr, v, nullptr, nullptr);
        k_qk_mfma<<<512, 256, 0, stream>>>(qh, ql, kh, kl, sc);
        k_vT<<<2048, 256, 0, stream>>>(v, vTb);
        k_softmax_b<<<1024, 256, 0, stream>>>(sc, scb);
        k_sv_mfma<<<1024, 256, 0, stream>>>(scb, vTb, o_pre);
        k_ln2<<<8192, 256, 0, stream>>>(o_pre, lng + i*1024, lnb + i*1024, oc_buf);
        k_conv<<<2048, 256, 0, stream>>>(oc_buf, cw + i*2304, cb + i*16, h, hn, nullptr, nullptr);
    }
}

// Round 4
// 981.116 us; speedup vs baseline: 3.1546x; 1.3759x over previous
//
#include <hip/hip_runtime.h>
#include <hip/hip_bf16.h>

typedef unsigned short u16;
typedef unsigned int   u32;
typedef short bf16x8 __attribute__((ext_vector_type(8)));
typedef float f32x4  __attribute__((ext_vector_type(4)));

#define SS 512

__device__ __forceinline__ float gelu_f(float v){
    return 0.5f * v * (1.0f + erff(v * 0.70710678118654752f));
}
__device__ __forceinline__ u16 bf16_rne(float v){
    u32 u = __float_as_uint(v);
    u32 r = u + 0x7FFF + ((u >> 16) & 1);
    return (u16)(r >> 16);
}
#define DYT(t) ((t)>=9 ? 0 : (t)/3)
#define DXT(t) ((t)>=9 ? 0 : (t)%3)

// ---------- embedding (padding_idx=0) + layernorm ----------
// writes f32 NCHW h[b][m][s][n] (d_out slice) and hi/lo bf16 [b][s][d'=n*16+m]
__global__ __launch_bounds__(256) void k_embed_ln(
    const int* __restrict__ x, const float* __restrict__ emb,
    const float* __restrict__ g, const float* __restrict__ bta,
    float* __restrict__ h, u16* __restrict__ hh, u16* __restrict__ hl)
{
    int bs = blockIdx.x;
    int b = bs >> 9, s = bs & 511;
    int t = x[bs];
    int tid = threadIdx.x;
    float v[4];
    #pragma unroll
    for (int j = 0; j < 4; ++j){
        int idx = tid + j*256;
        v[j] = (t == 0) ? 0.0f : emb[(size_t)t*1024 + idx];
    }
    float sum = v[0]+v[1]+v[2]+v[3];
    float sq  = v[0]*v[0]+v[1]*v[1]+v[2]*v[2]+v[3]*v[3];
    __shared__ float red[2][4];
    int lane = tid & 63, wid = tid >> 6;
    #pragma unroll
    for (int off = 32; off; off >>= 1){
        sum += __shfl_down(sum, off, 64);
        sq  += __shfl_down(sq,  off, 64);
    }
    if (lane == 0){ red[0][wid] = sum; red[1][wid] = sq; }
    __syncthreads();
    sum = red[0][0]+red[0][1]+red[0][2]+red[0][3];
    sq  = red[1][0]+red[1][1]+red[1][2]+red[1][3];
    float mean = sum * (1.0f/1024.0f);
    float var  = sq  * (1.0f/1024.0f) - mean*mean;
    float rs = rsqrtf(var + 1e-5f);
    #pragma unroll
    for (int j = 0; j < 4; ++j){
        int idx = tid + j*256;
        float y = (v[j]-mean)*rs*g[idx] + bta[idx];
        int m = idx >> 6, n = idx & 63;
        h[((size_t)(b*16 + m)*SS + s)*64 + n] = y;
        u16 hv = bf16_rne(y);
        u16 lv = bf16_rne(y - __uint_as_float((u32)hv<<16));
        size_t da = ((size_t)b*SS + s)*1024 + n*16 + m;
        hh[da] = hv; hl[da] = lv;
    }
}

// ---------- conv 3x3 via MFMA implicit GEMM ----------
// input: hi(/lo) bf16 [b][y][x*16+ch]; weights f32 w[o][i][ky][kx]
// out: bf16 hi(/lo) [b][y][x*16+o]; RES: also f32 NCHW residual add + store
template<bool SPLIT_IN, bool SPLIT_OUT, bool RES>
__global__ __launch_bounds__(256) void k_conv_mfma(
    const u16* __restrict__ inh, const u16* __restrict__ inl,
    const float* __restrict__ w, const float* __restrict__ bias,
    const float* __restrict__ resid, float* __restrict__ outf,
    u16* __restrict__ outh, u16* __restrict__ outl)
{
    int bid = blockIdx.x;                 // 16 b x 64 ytiles
    int b  = bid >> 6;
    int y0 = (bid & 63) * 8;
    int tid = threadIdx.x;
    int w4 = tid >> 6, lane = tid & 63;
    int l15 = lane & 15, l4 = lane >> 4;

    __shared__ u16 whi[16*160];
    __shared__ u16 wlo[SPLIT_IN ? 16*160 : 1];
    __shared__ u16 shi[10*68*24];
    __shared__ u16 slo[SPLIT_IN ? 10*68*24 : 1];

    // stage weights, split hi/lo, layout [o][k=tap*16+i], K padded to 160
    for (int idx = tid; idx < 2304; idx += 256){
        int o = idx / 144, rem = idx - o*144;
        int i = rem / 9, tap = rem - i*9;
        float wv = w[idx];
        u16 hv = bf16_rne(wv);
        int dst = o*160 + tap*16 + i;
        whi[dst] = hv;
        if (SPLIT_IN) wlo[dst] = bf16_rne(wv - __uint_as_float((u32)hv<<16));
    }
    {   // zero pad taps (k=144..159)
        int o = tid >> 4, kk = tid & 15;
        if (tid < 256){
            whi[o*160 + 144 + kk] = 0;
            if (SPLIT_IN) wlo[o*160 + 144 + kk] = 0;
        }
    }
    // zero x-halo cols (tc=0, tc=65)
    if (tid < 40){
        int y = tid >> 2, rr = tid & 3;
        int tc = (rr >> 1) ? 65 : 0;
        int h8 = (rr & 1) * 8;
        int ad = (y*68 + tc)*24 + h8;
        *(uint4*)&shi[ad] = make_uint4(0,0,0,0);
        if (SPLIT_IN) *(uint4*)&slo[ad] = make_uint4(0,0,0,0);
    }
    // stage input rows y0-1 .. y0+8 (10 rows x 64 x x 16 ch)
    #pragma unroll
    for (int it = 0; it < 5; ++it){
        int idx = tid + it*256;           // 0..1279
        int y = idx >> 7;
        int rem = idx & 127;
        int xx = rem >> 1, h8 = (rem & 1)*8;
        int gy = y0 - 1 + y;
        uint4 vh = make_uint4(0,0,0,0), vl = make_uint4(0,0,0,0);
        if (gy >= 0 && gy < SS){
            size_t ga = ((size_t)b*SS + gy)*1024 + xx*16 + h8;
            vh = *(const uint4*)(inh + ga);
            if (SPLIT_IN) vl = *(const uint4*)(inl + ga);
        }
        int la = (y*68 + (xx+1))*24 + h8;
        *(uint4*)&shi[la] = vh;
        if (SPLIT_IN) *(uint4*)&slo[la] = vl;
    }
    __syncthreads();

    bf16x8 ah[5], al[5];
    #pragma unroll
    for (int p = 0; p < 5; ++p){
        int aad = l15*160 + p*32 + l4*8;
        ah[p] = *(const bf16x8*)&whi[aad];
        if (SPLIT_IN) al[p] = *(const bf16x8*)&wlo[aad];
    }

    f32x4 acc[8];
    #pragma unroll
    for (int i = 0; i < 8; ++i) acc[i] = (f32x4){0.f,0.f,0.f,0.f};
    int hsel = l4 >> 1;
    int i0 = (l4 & 1)*8;
    int xo = w4*16 + l15;                 // this wave owns x-tile w4

    #pragma unroll
    for (int p = 0; p < 5; ++p){
        int dy = hsel ? DYT(2*p+1) : DYT(2*p);
        int dx = hsel ? DXT(2*p+1) : DXT(2*p);
        int badd0 = (dy*68 + xo + dx)*24 + i0;
        #pragma unroll
        for (int yy = 0; yy < 8; ++yy){
            int bad = badd0 + yy*(68*24);
            bf16x8 bh = *(const bf16x8*)&shi[bad];
            acc[yy] = __builtin_amdgcn_mfma_f32_16x16x32_bf16(ah[p], bh, acc[yy],0,0,0);
            if (SPLIT_IN){
                bf16x8 bl = *(const bf16x8*)&slo[bad];
                acc[yy] = __builtin_amdgcn_mfma_f32_16x16x32_bf16(al[p], bh, acc[yy],0,0,0);
                acc[yy] = __builtin_amdgcn_mfma_f32_16x16x32_bf16(ah[p], bl, acc[yy],0,0,0);
            }
        }
    }

    float bv[4];
    #pragma unroll
    for (int i = 0; i < 4; ++i) bv[i] = bias[l4*4 + i];
    #pragma unroll
    for (int yy = 0; yy < 8; ++yy){
        int y = y0 + yy;
        float r[4];
        #pragma unroll
        for (int i = 0; i < 4; ++i) r[i] = gelu_f(acc[yy][i] + bv[i]);
        if (RES){
            #pragma unroll
            for (int i = 0; i < 4; ++i){
                int o = l4*4 + i;
                size_t fa = ((size_t)(b*16 + o)*SS + y)*64 + xo;
                float hv = resid[fa] + r[i];
                outf[fa] = hv;
                r[i] = hv;
            }
        }
        u16 hh_[4], ll_[4];
        #pragma unroll
        for (int i = 0; i < 4; ++i){
            hh_[i] = bf16_rne(r[i]);
            if (SPLIT_OUT) ll_[i] = bf16_rne(r[i] - __uint_as_float((u32)hh_[i]<<16));
        }
        size_t oa = ((size_t)b*SS + y)*1024 + xo*16 + l4*4;
        *(uint2*)&outh[oa] = make_uint2((u32)hh_[0]|((u32)hh_[1]<<16),(u32)hh_[2]|((u32)hh_[3]<<16));
        if (SPLIT_OUT)
            *(uint2*)&outl[oa] = make_uint2((u32)ll_[0]|((u32)ll_[1]<<16),(u32)ll_[2]|((u32)ll_[3]<<16));
    }
}

// ---------- QK^T via MFMA, split-bf16 (3 products); act layout [b][s][d'] ----------
__global__ __launch_bounds__(256) void k_qk_mfma(
    const u16* __restrict__ qh, const u16* __restrict__ ql,
    const u16* __restrict__ kh, const u16* __restrict__ kl,
    float* __restrict__ score)
{
    int bid = blockIdx.x;                 // 16b x 4 s1t x 8 s2t = 512
    int b = bid >> 5;
    int s1_0 = ((bid >> 3) & 3) * 128;
    int s2_0 = (bid & 7) * 64;
    __shared__ u16 Ah[128][72], Al[128][72], Bh[64][72], Bl[64][72];
    int tid = threadIdx.x;
    int w = tid >> 6, lane = tid & 63;
    int l15 = lane & 15, l4 = lane >> 4;
    f32x4 acc[2][4];
    #pragma unroll
    for (int r=0;r<2;++r)
        #pragma unroll
        for(int c=0;c<4;++c) acc[r][c] = (f32x4){0.f,0.f,0.f,0.f};

    for (int oc = 0; oc < 16; ++oc){
        size_t qbase = ((size_t)b*SS + s1_0)*1024 + oc*64;
        size_t kbase = ((size_t)b*SS + s2_0)*1024 + oc*64;
        #pragma unroll
        for (int i = 0; i < 4; ++i){
            int idx = tid + i*256;
            int r = idx >> 3, f = idx & 7;
            *(uint4*)&Ah[r][f*8] = *(const uint4*)(qh + qbase + (size_t)r*1024 + f*8);
            *(uint4*)&Al[r][f*8] = *(const uint4*)(ql + qbase + (size_t)r*1024 + f*8);
        }
        #pragma unroll
        for (int i = 0; i < 2; ++i){
            int idx = tid + i*256;
            int r = idx >> 3, f = idx & 7;
            *(uint4*)&Bh[r][f*8] = *(const uint4*)(kh + kbase + (size_t)r*1024 + f*8);
            *(uint4*)&Bl[r][f*8] = *(const uint4*)(kl + kbase + (size_t)r*1024 + f*8);
        }
        __syncthreads();
        #pragma unroll
        for (int ks = 0; ks < 2; ++ks){
            bf16x8 a_h[2], a_l[2];
            #pragma unroll
            for (int r=0;r<2;++r){
                a_h[r] = *(const bf16x8*)&Ah[w*32 + r*16 + l15][ks*32 + l4*8];
                a_l[r] = *(const bf16x8*)&Al[w*32 + r*16 + l15][ks*32 + l4*8];
            }
            #pragma unroll
            for (int c=0;c<4;++c){
                bf16x8 b_h = *(const bf16x8*)&Bh[c*16 + l15][ks*32 + l4*8];
                bf16x8 b_l = *(const bf16x8*)&Bl[c*16 + l15][ks*32 + l4*8];
                #pragma unroll
                for (int r=0;r<2;++r){
                    acc[r][c] = __builtin_amdgcn_mfma_f32_16x16x32_bf16(a_h[r], b_h, acc[r][c],0,0,0);
                    acc[r][c] = __builtin_amdgcn_mfma_f32_16x16x32_bf16(a_l[r], b_h, acc[r][c],0,0,0);
                    acc[r][c] = __builtin_amdgcn_mfma_f32_16x16x32_bf16(a_h[r], b_l, acc[r][c],0,0,0);
                }
            }
        }
        __syncthreads();
    }
    #pragma unroll
    for (int r=0;r<2;++r)
        #pragma unroll
        for (int c=0;c<4;++c)
            #pragma unroll
            for (int i=0;i<4;++i){
                int s1 = s1_0 + w*32 + r*16 + l4*4 + i;
                int s2 = s2_0 + c*16 + l15;
                score[((size_t)b*SS + s1)*SS + s2] = acc[r][c][i];
            }
}

// ---------- vT[b][d'][s2] from v[b][s2][d'] (both bf16) ----------
__global__ __launch_bounds__(256) void k_vT(
    const u16* __restrict__ v, u16* __restrict__ vT)
{
    int bid = blockIdx.x;                 // 16b x 16 d'chunk x 8 s2blk
    int b  = bid >> 7;
    int dc = (bid >> 3) & 15;
    int sb = bid & 7;
    int tid = threadIdx.x;
    int dl = tid & 63;
    int sg = tid >> 6;
    int d0 = dc*64 + dl;
    int s2base = sb*64 + sg*16;
    union { u16 u[16]; uint4 q[2]; } pk;
    #pragma unroll
    for (int j = 0; j < 16; ++j)
        pk.u[j] = v[((size_t)b*SS + s2base + j)*1024 + d0];
    u16* dst = vT + ((size_t)b*1024 + d0)*SS + s2base;
    *(uint4*)dst       = pk.q[0];
    *(uint4*)(dst + 8) = pk.q[1];
}

// ---------- softmax over batch axis; writes bf16 probs ----------
__global__ __launch_bounds__(256) void k_softmax_b(
    const float* __restrict__ score, u16* __restrict__ scb)
{
    int sid = blockIdx.x*256 + threadIdx.x;
    float vals[16];
    float m = -1e30f;
    #pragma unroll
    for (int b = 0; b < 16; ++b){
        vals[b] = score[(size_t)b*SS*SS + sid];
        m = fmaxf(m, vals[b]);
    }
    float sum = 0.f;
    #pragma unroll
    for (int b = 0; b < 16; ++b){ vals[b] = __expf(vals[b]-m); sum += vals[b]; }
    float inv = 1.0f/sum;
    #pragma unroll
    for (int b = 0; b < 16; ++b) scb[(size_t)b*SS*SS + sid] = bf16_rne(vals[b]*inv);
}

// ---------- o_pre[b,s1,d'] = sum_s2 P[b,s1,s2] * vT[b,d',s2] ----------
__global__ __launch_bounds__(256) void k_sv_mfma(
    const u16* __restrict__ scb, const u16* __restrict__ vT,
    float* __restrict__ o)
{
    int bid = blockIdx.x;                 // 16b x 4 s1t x 16 dt
    int b = bid >> 6;
    int s1_0 = ((bid >> 4) & 3) * 128;
    int d0 = (bid & 15) * 64;
    __shared__ u16 As[128][72], Bs[64][72];
    int tid = threadIdx.x;
    int w = tid >> 6, lane = tid & 63;
    int l15 = lane & 15, l4 = lane >> 4;
    f32x4 acc[2][4];
    #pragma unroll
    for (int r=0;r<2;++r)
        #pragma unroll
        for(int c=0;c<4;++c) acc[r][c] = (f32x4){0.f,0.f,0.f,0.f};

    for (int st = 0; st < 8; ++st){
        int s2b = st*64;
        #pragma unroll
        for (int i = 0; i < 4; ++i){
            int idx = tid + i*256;
            int r = idx >> 3, f = idx & 7;
            *(uint4*)&As[r][f*8] = *(const uint4*)(scb + ((size_t)b*SS + s1_0 + r)*SS + s2b + f*8);
        }
        #pragma unroll
        for (int i = 0; i < 2; ++i){
            int idx = tid + i*256;
            int r = idx >> 3, f = idx & 7;
            *(uint4*)&Bs[r][f*8] = *(const uint4*)(vT + ((size_t)b*1024 + d0 + r)*SS + s2b + f*8);
        }
        __syncthreads();
        #pragma unroll
        for (int ks = 0; ks < 2; ++ks){
            bf16x8 a0[2];
            #pragma unroll
            for (int r=0;r<2;++r)
                a0[r] = *(const bf16x8*)&As[w*32 + r*16 + l15][ks*32 + l4*8];
            #pragma unroll
            for (int c=0;c<4;++c){
                bf16x8 b0 = *(const bf16x8*)&Bs[c*16 + l15][ks*32 + l4*8];
                #pragma unroll
                for (int r=0;r<2;++r)
                    acc[r][c] = __builtin_amdgcn_mfma_f32_16x16x32_bf16(a0[r], b0, acc[r][c],0,0,0);
            }
        }
        __syncthreads();
    }
    #pragma unroll
    for (int r=0;r<2;++r)
        #pragma unroll
        for (int c=0;c<4;++c)
            #pragma unroll
            for (int i=0;i<4;++i){
                int s1 = s1_0 + w*32 + r*16 + l4*4 + i;
                o[((size_t)b*SS + s1)*1024 + d0 + c*16 + l15] = acc[r][c][i];
            }
}

// ---------- layernorm over d' (1024), gamma/beta index-remapped; hi/lo out ----------
__global__ __launch_bounds__(256) void k_ln2(
    const float* __restrict__ o, const float* __restrict__ g,
    const float* __restrict__ bta, u16* __restrict__ och, u16* __restrict__ ocl)
{
    int bs = blockIdx.x;
    int tid = threadIdx.x;
    const float* row = o + (size_t)bs*1024;
    float v[4];
    #pragma unroll
    for (int j = 0; j < 4; ++j) v[j] = row[tid + j*256];
    float sum = v[0]+v[1]+v[2]+v[3];
    float sq  = v[0]*v[0]+v[1]*v[1]+v[2]*v[2]+v[3]*v[3];
    __shared__ float red[2][4];
    int lane = tid & 63, wid = tid >> 6;
    #pragma unroll
    for (int off = 32; off; off >>= 1){
        sum += __shfl_down(sum, off, 64);
        sq  += __shfl_down(sq,  off, 64);
    }
    if (lane == 0){ red[0][wid] = sum; red[1][wid] = sq; }
    __syncthreads();
    sum = red[0][0]+red[0][1]+red[0][2]+red[0][3];
    sq  = red[1][0]+red[1][1]+red[1][2]+red[1][3];
    float mean = sum * (1.0f/1024.0f);
    float var  = sq  * (1.0f/1024.0f) - mean*mean;
    float rs = rsqrtf(var + 1e-5f);
    #pragma unroll
    for (int j = 0; j < 4; ++j){
        int idx = tid + j*256;                    // d'
        int od = (idx & 15)*64 + (idx >> 4);      // original d = m*64+n
        float y = (v[j]-mean)*rs*g[od] + bta[od];
        u16 hv = bf16_rne(y);
        och[(size_t)bs*1024 + idx] = hv;
        ocl[(size_t)bs*1024 + idx] = bf16_rne(y - __uint_as_float((u32)hv<<16));
    }
}

extern "C" void kernel_launch(void* const* d_in, const int* in_sizes, int n_in,
                              void* d_out, int out_size, void* d_ws, size_t ws_size,
                              hipStream_t stream)
{
    const int*   x    = (const int*)  d_in[0];
    const float* emb  = (const float*)d_in[1];
    const float* g0   = (const float*)d_in[2];
    const float* b0   = (const float*)d_in[3];
    const float* qw   = (const float*)d_in[4];
    const float* qb   = (const float*)d_in[5];
    const float* kw   = (const float*)d_in[6];
    const float* kb   = (const float*)d_in[7];
    const float* vw   = (const float*)d_in[8];
    const float* vb_  = (const float*)d_in[9];
    const float* lng  = (const float*)d_in[10];
    const float* lnb  = (const float*)d_in[11];
    const float* cw   = (const float*)d_in[12];
    const float* cb   = (const float*)d_in[13];
    float* out = (float*)d_out;

    const size_t TS = (size_t)16*16*512*64;       // 8388608
    u16* wsu = (u16*)d_ws;
    // 8 slots of TS u16 (16.8 MB each)
    u16* hh = wsu + 0*TS;
    u16* hl = wsu + 1*TS;
    u16* qh = wsu + 2*TS;
    u16* ql = wsu + 3*TS;
    u16* kh = wsu + 4*TS;
    u16* kl = wsu + 5*TS;
    u16* vb = wsu + 6*TS;
    float* sc    = (float*)(wsu + 7*TS);          // 16*512*512 f32 = 1 slot
    u16*   scb   = qh;                            // after qk, qh dead
    u16*   vTb   = ql;                            // after qk, ql dead
    float* o_pre = (float*)(wsu + 4*TS);          // slots 4+5 (kh,kl dead after qk)
    u16*   och   = qh;                            // after sv, scb dead
    u16*   ocl   = ql;                            // after sv, vT dead

    float* hbuf[5];
    hbuf[0] = out + 1*TS;
    hbuf[1] = out + 2*TS;
    hbuf[2] = out + 3*TS;
    hbuf[3] = out + 4*TS;
    hbuf[4] = out;

    k_embed_ln<<<8192, 256, 0, stream>>>(x, emb, g0, b0, hbuf[0], hh, hl);
    for (int i = 0; i < 4; ++i){
        k_conv_mfma<true,true,false><<<1024, 256, 0, stream>>>(
            hh, hl, qw + i*2304, qb + i*16, nullptr, nullptr, qh, ql);
        k_conv_mfma<true,true,false><<<1024, 256, 0, stream>>>(
            hh, hl, kw + i*2304, kb + i*16, nullptr, nullptr, kh, kl);
        k_conv_mfma<false,false,false><<<1024, 256, 0, stream>>>(
            hh, nullptr, vw + i*2304, vb_ + i*16, nullptr, nullptr, vb, nullptr);
        k_qk_mfma<<<512, 256, 0, stream>>>(qh, ql, kh, kl, sc);
        k_vT<<<2048, 256, 0, stream>>>(vb, vTb);
        k_softmax_b<<<1024, 256, 0, stream>>>(sc, scb);
        k_sv_mfma<<<1024, 256, 0, stream>>>(scb, vTb, o_pre);
        k_ln2<<<8192, 256, 0, stream>>>(o_pre, lng + i*1024, lnb + i*1024, och, ocl);
        k_conv_mfma<true,true,true><<<1024, 256, 0, stream>>>(
            och, ocl, cw + i*2304, cb + i*16, hbuf[i], hbuf[i+1], hh, hl);
    }
}